// Round 1
// baseline (279.673 us; speedup 1.0000x reference)
//
#include <hip/hip_runtime.h>

typedef unsigned short u16;
typedef unsigned int   u32;
typedef __bf16 bf16x8 __attribute__((ext_vector_type(8)));
typedef float  f32x4  __attribute__((ext_vector_type(4)));

#define DEVI __device__ __forceinline__

DEVI u16 f2bf(float f) {
    union { float f; u32 u; } c; c.f = f;
    u32 u = c.u;
    u32 r = (u + 0x7fffu + ((u >> 16) & 1u)) >> 16;
    return (u16)r;
}
DEVI float bf2f(u16 v) {
    union { u32 u; float f; } c; c.u = ((u32)v) << 16;
    return c.f;
}

DEVI void gload16(const void* g, void* l) {
    __builtin_amdgcn_global_load_lds(
        (const __attribute__((address_space(1))) void*)g,
        (__attribute__((address_space(3))) void*)l, 16, 0, 0);
}

// ---------------- conversions ----------------

__global__ __launch_bounds__(256) void k_cvt_x(const float4* __restrict__ x,
                                               uint2* __restrict__ o, int n4) {
    int i = blockIdx.x * 256 + threadIdx.x;
    if (i < n4) {
        float4 v = x[i];
        uint2 r;
        r.x = (u32)f2bf(v.x) | ((u32)f2bf(v.y) << 16);
        r.y = (u32)f2bf(v.z) | ((u32)f2bf(v.w) << 16);
        o[i] = r;
    }
}

// wt[c][r] = bf16(w[r][c]);  w is [R][C] fp32
__global__ __launch_bounds__(256) void k_transpose_bf(const float* __restrict__ w,
                                                      u16* __restrict__ wt, int R, int C) {
    __shared__ float t[32][33];
    int c0 = blockIdx.x * 32, r0 = blockIdx.y * 32;
    int x = threadIdx.x & 31, y = threadIdx.x >> 5;  // 32 x 8
    for (int i = y; i < 32; i += 8) t[i][x] = w[(size_t)(r0 + i) * C + c0 + x];
    __syncthreads();
    for (int i = y; i < 32; i += 8) wt[(size_t)(c0 + i) * R + r0 + x] = f2bf(t[x][i]);
}

// ---------------- fused dual GEMM: pre_gate / pre_inp -> a, b (bf16) ----------------
// A: [M,K] bf16 row-major.  Bg,Bi: [N,K] bf16 row-major (pre-transposed weights).
// a = sigmoid(A@gw + gb); b = (1-a)*(A@iw + ib)

__global__ __launch_bounds__(256) void k_gemm_gate(
    const u16* __restrict__ A, const u16* __restrict__ Bg, const u16* __restrict__ Bi,
    const float* __restrict__ gb, const float* __restrict__ ib,
    u16* __restrict__ aout, u16* __restrict__ bout, int M, int N, int K) {
    __shared__ __align__(16) u16 sA[128 * 64];
    __shared__ __align__(16) u16 sG[128 * 64];
    __shared__ __align__(16) u16 sI[128 * 64];
    const int tid = threadIdx.x, lane = tid & 63, wv = tid >> 6;
    const int wr = wv >> 1, wc = wv & 1;
    const long bm = blockIdx.y, bn = blockIdx.x;
    const u16* Ab = A + bm * 128 * (long)K;
    const u16* Gb = Bg + bn * 128 * (long)K;
    const u16* Ib = Bi + bn * 128 * (long)K;

    f32x4 accg[4][4] = {};
    f32x4 acci[4][4] = {};

    for (int kt = 0; kt < K; kt += 64) {
#pragma unroll
        for (int p = 0; p < 4; ++p) {
            int chunk = p * 256 + tid;            // 16B chunk id, 1024 per tile
            int row = chunk >> 3, kc = (chunk & 7) << 3;
            int lbase = (p * 256 + (wv << 6)) << 3;  // wave-uniform LDS base (u16 units)
            long goff = (long)row * K + kt + kc;
            gload16(Ab + goff, sA + lbase);
            gload16(Gb + goff, sG + lbase);
            gload16(Ib + goff, sI + lbase);
        }
        __syncthreads();
#pragma unroll
        for (int kk = 0; kk < 2; ++kk) {
            const int ko = kk * 32 + ((lane >> 4) << 3);
            const int r = lane & 15;
            bf16x8 af[4], gf[4], pf[4];
#pragma unroll
            for (int m = 0; m < 4; ++m)
                af[m] = *(const bf16x8*)&sA[((wr * 64 + m * 16 + r) << 6) + ko];
#pragma unroll
            for (int n = 0; n < 4; ++n) {
                gf[n] = *(const bf16x8*)&sG[((wc * 64 + n * 16 + r) << 6) + ko];
                pf[n] = *(const bf16x8*)&sI[((wc * 64 + n * 16 + r) << 6) + ko];
            }
#pragma unroll
            for (int m = 0; m < 4; ++m)
#pragma unroll
                for (int n = 0; n < 4; ++n) {
                    accg[m][n] = __builtin_amdgcn_mfma_f32_16x16x32_bf16(af[m], gf[n], accg[m][n], 0, 0, 0);
                    acci[m][n] = __builtin_amdgcn_mfma_f32_16x16x32_bf16(af[m], pf[n], acci[m][n], 0, 0, 0);
                }
        }
        __syncthreads();
    }

    const long mbase = bm * 128 + wr * 64;
    const int nbase = (int)bn * 128 + wc * 64;
#pragma unroll
    for (int n = 0; n < 4; ++n) {
        int col = nbase + n * 16 + (lane & 15);
        float g0 = gb[col], i0 = ib[col];
#pragma unroll
        for (int m = 0; m < 4; ++m) {
            long row = mbase + m * 16 + ((lane >> 4) << 2);
#pragma unroll
            for (int i = 0; i < 4; ++i) {
                float pg = accg[m][n][i] + g0;
                float pi = acci[m][n][i] + i0;
                float aa = 1.0f / (1.0f + __expf(-pg));
                float bb = (1.0f - aa) * pi;
                long o = (row + i) * (long)N + col;
                aout[o] = f2bf(aa);
                bout[o] = f2bf(bb);
            }
        }
    }
}

// ---------------- final GEMM: out = h @ out_w + x + out_b ----------------

__global__ __launch_bounds__(256) void k_gemm_out(
    const u16* __restrict__ A, const u16* __restrict__ Bt,
    const float* __restrict__ xres, const float* __restrict__ ob,
    float* __restrict__ out, int M, int N, int K) {
    __shared__ __align__(16) u16 sA[128 * 64];
    __shared__ __align__(16) u16 sB[128 * 64];
    const int tid = threadIdx.x, lane = tid & 63, wv = tid >> 6;
    const int wr = wv >> 1, wc = wv & 1;
    const long bm = blockIdx.y, bn = blockIdx.x;
    const u16* Ab = A + bm * 128 * (long)K;
    const u16* Bb = Bt + bn * 128 * (long)K;

    f32x4 acc[4][4] = {};

    for (int kt = 0; kt < K; kt += 64) {
#pragma unroll
        for (int p = 0; p < 4; ++p) {
            int chunk = p * 256 + tid;
            int row = chunk >> 3, kc = (chunk & 7) << 3;
            int lbase = (p * 256 + (wv << 6)) << 3;
            long goff = (long)row * K + kt + kc;
            gload16(Ab + goff, sA + lbase);
            gload16(Bb + goff, sB + lbase);
        }
        __syncthreads();
#pragma unroll
        for (int kk = 0; kk < 2; ++kk) {
            const int ko = kk * 32 + ((lane >> 4) << 3);
            const int r = lane & 15;
            bf16x8 af[4], bf[4];
#pragma unroll
            for (int m = 0; m < 4; ++m)
                af[m] = *(const bf16x8*)&sA[((wr * 64 + m * 16 + r) << 6) + ko];
#pragma unroll
            for (int n = 0; n < 4; ++n)
                bf[n] = *(const bf16x8*)&sB[((wc * 64 + n * 16 + r) << 6) + ko];
#pragma unroll
            for (int m = 0; m < 4; ++m)
#pragma unroll
                for (int n = 0; n < 4; ++n)
                    acc[m][n] = __builtin_amdgcn_mfma_f32_16x16x32_bf16(af[m], bf[n], acc[m][n], 0, 0, 0);
        }
        __syncthreads();
    }

    const long mbase = bm * 128 + wr * 64;
    const int nbase = (int)bn * 128 + wc * 64;
#pragma unroll
    for (int n = 0; n < 4; ++n) {
        int col = nbase + n * 16 + (lane & 15);
        float o0 = ob[col];
#pragma unroll
        for (int m = 0; m < 4; ++m) {
            long row = mbase + m * 16 + ((lane >> 4) << 2);
#pragma unroll
            for (int i = 0; i < 4; ++i) {
                long o = (row + i) * (long)N + col;
                out[o] = acc[m][n][i] + o0 + xres[o];
            }
        }
    }
}

// ---------------- chunked affine scan ----------------
// h_t = a_t * h_{t-1} + b_t over s in [0,4096), per (batch, channel).
// 64 chunks x 64 steps. Channels processed 2-per-thread (u32 = 2 x bf16).

#define SCAN_C 64
#define SCAN_L 64

__global__ __launch_bounds__(256) void k_scan_phaseA(
    const u32* __restrict__ a, const u32* __restrict__ b,
    float2* __restrict__ cA, float2* __restrict__ cB) {
    int e2 = blockIdx.x * 256 + threadIdx.x;  // 0..511  (channel pair)
    int c = blockIdx.y, bt = blockIdx.z;
    long base = ((long)bt * 4096 + (long)c * SCAN_L) * 512 + e2;
    float A0 = 1.f, A1 = 1.f, H0 = 0.f, H1 = 0.f;
#pragma unroll 4
    for (int i = 0; i < SCAN_L; ++i) {
        u32 av = a[base + (long)i * 512];
        u32 bv = b[base + (long)i * 512];
        float a0 = bf2f((u16)av), a1 = bf2f((u16)(av >> 16));
        float b0 = bf2f((u16)bv), b1 = bf2f((u16)(bv >> 16));
        H0 = a0 * H0 + b0;  H1 = a1 * H1 + b1;
        A0 *= a0;           A1 *= a1;
    }
    long sidx = ((long)bt * SCAN_C + c) * 512 + e2;
    cA[sidx] = make_float2(A0, A1);
    cB[sidx] = make_float2(H0, H1);
}

__global__ __launch_bounds__(256) void k_scan_phaseB(
    const float2* __restrict__ cA, const float2* __restrict__ cB,
    float2* __restrict__ hin) {
    int e2 = blockIdx.x * 256 + threadIdx.x;  // 0..511
    int bt = blockIdx.y;
    float H0 = 0.f, H1 = 0.f;
    for (int c = 0; c < SCAN_C; ++c) {
        long idx = ((long)bt * SCAN_C + c) * 512 + e2;
        hin[idx] = make_float2(H0, H1);
        float2 Av = cA[idx], Bv = cB[idx];
        H0 = Av.x * H0 + Bv.x;
        H1 = Av.y * H1 + Bv.y;
    }
}

__global__ __launch_bounds__(256) void k_scan_phaseC(
    const u32* __restrict__ a, const u32* __restrict__ b,
    const float2* __restrict__ hin, u32* __restrict__ hout) {
    int e2 = blockIdx.x * 256 + threadIdx.x;
    int c = blockIdx.y, bt = blockIdx.z;
    long base = ((long)bt * 4096 + (long)c * SCAN_L) * 512 + e2;
    long sidx = ((long)bt * SCAN_C + c) * 512 + e2;
    float2 H = hin[sidx];
    float H0 = H.x, H1 = H.y;
#pragma unroll 4
    for (int i = 0; i < SCAN_L; ++i) {
        u32 av = a[base + (long)i * 512];
        u32 bv = b[base + (long)i * 512];
        float a0 = bf2f((u16)av), a1 = bf2f((u16)(av >> 16));
        float b0 = bf2f((u16)bv), b1 = bf2f((u16)(bv >> 16));
        H0 = a0 * H0 + b0;  H1 = a1 * H1 + b1;
        hout[base + (long)i * 512] = (u32)f2bf(H0) | ((u32)f2bf(H1) << 16);
    }
}

// ---------------- launch ----------------

extern "C" void kernel_launch(void* const* d_in, const int* in_sizes, int n_in,
                              void* d_out, int out_size, void* d_ws, size_t ws_size,
                              hipStream_t stream) {
    const float* x      = (const float*)d_in[0];
    const float* gate_w = (const float*)d_in[1];
    const float* gate_b = (const float*)d_in[2];
    const float* inp_w  = (const float*)d_in[3];
    const float* inp_b  = (const float*)d_in[4];
    const float* out_w  = (const float*)d_in[5];
    const float* out_b  = (const float*)d_in[6];
    float* out = (float*)d_out;

    const int Bsz = 4, S = 4096, Din = 1024, Dst = 1024;
    const int M = Bsz * S;                 // 16384
    const long nx = (long)M * Din;         // 16777216

    // workspace layout (bytes)
    char* w = (char*)d_ws;
    u16* xb     = (u16*)(w);                  // 33,554,432  x bf16
    u16* gwT    = (u16*)(w + 33554432);       //  2,097,152  gate_w^T bf16
    u16* iwT    = (u16*)(w + 35651584);       //  2,097,152  inp_w^T  bf16
    u16* owT    = (u16*)(w + 37748736);       //  2,097,152  out_w^T  bf16
    u16* hbf    = (u16*)(w + 39845888);       // 33,554,432  scan_out bf16
    float2* cA  = (float2*)(w + 73400320);    //  1,048,576  chunk A-products
    float2* cB  = (float2*)(w + 74448896);    //  1,048,576  chunk B-offsets
    float2* hin = (float2*)(w + 75497472);    //  1,048,576  chunk incoming states
    // total 76,546,048 B

    // a, b (bf16) live in d_out (exactly 67,108,864 B); overwritten by final GEMM.
    u16* abf = (u16*)d_out;
    u16* bbf = abf + nx;

    // 1. conversions
    k_cvt_x<<<(int)(nx / 4 / 256), 256, 0, stream>>>((const float4*)x, (uint2*)xb, (int)(nx / 4));
    dim3 tg(Dst / 32, Din / 32);
    k_transpose_bf<<<tg, 256, 0, stream>>>(gate_w, gwT, Din, Dst);
    k_transpose_bf<<<tg, 256, 0, stream>>>(inp_w, iwT, Din, Dst);
    k_transpose_bf<<<dim3(Din / 32, Dst / 32), 256, 0, stream>>>(out_w, owT, Dst, Din);

    // 2. fused dual GEMM -> a, b
    k_gemm_gate<<<dim3(Dst / 128, M / 128), 256, 0, stream>>>(
        xb, gwT, iwT, gate_b, inp_b, abf, bbf, M, Dst, Din);

    // 3. chunked scan -> h (bf16)
    k_scan_phaseA<<<dim3(2, SCAN_C, Bsz), 256, 0, stream>>>((const u32*)abf, (const u32*)bbf, cA, cB);
    k_scan_phaseB<<<dim3(2, Bsz), 256, 0, stream>>>(cA, cB, hin);
    k_scan_phaseC<<<dim3(2, SCAN_C, Bsz), 256, 0, stream>>>((const u32*)abf, (const u32*)bbf, hin, (u32*)hbf);

    // 4. final GEMM: out = h @ out_w + x + out_b
    k_gemm_out<<<dim3(Din / 128, M / 128), 256, 0, stream>>>(
        hbf, owT, x, out_b, out, M, Din, Dst);
}

// Round 2
// 233.669 us; speedup vs baseline: 1.1969x; 1.1969x over previous
//
#include <hip/hip_runtime.h>

typedef unsigned short u16;
typedef unsigned int   u32;
typedef __bf16 bf16x8 __attribute__((ext_vector_type(8)));
typedef float  f32x4  __attribute__((ext_vector_type(4)));

#define DEVI __device__ __forceinline__

DEVI u16 f2bf(float f) {
    union { float f; u32 u; } c; c.f = f;
    u32 u = c.u;
    u32 r = (u + 0x7fffu + ((u >> 16) & 1u)) >> 16;
    return (u16)r;
}
DEVI float bf2f(u16 v) {
    union { u32 u; float f; } c; c.u = ((u32)v) << 16;
    return c.f;
}

DEVI void gload16(const void* g, void* l) {
    __builtin_amdgcn_global_load_lds(
        (const __attribute__((address_space(1))) void*)g,
        (__attribute__((address_space(3))) void*)l, 16, 0, 0);
}

// ---------------- conversions ----------------

__global__ __launch_bounds__(256) void k_cvt_x(const float4* __restrict__ x,
                                               uint2* __restrict__ o, int n4) {
    int i = blockIdx.x * 256 + threadIdx.x;
    if (i < n4) {
        float4 v = x[i];
        uint2 r;
        r.x = (u32)f2bf(v.x) | ((u32)f2bf(v.y) << 16);
        r.y = (u32)f2bf(v.z) | ((u32)f2bf(v.w) << 16);
        o[i] = r;
    }
}

// wt[c][r] = bf16(w[r][c]);  w is [R][C] fp32   (for out_w)
__global__ __launch_bounds__(256) void k_transpose_bf(const float* __restrict__ w,
                                                      u16* __restrict__ wt, int R, int C) {
    __shared__ float t[32][33];
    int c0 = blockIdx.x * 32, r0 = blockIdx.y * 32;
    int x = threadIdx.x & 31, y = threadIdx.x >> 5;  // 32 x 8
    for (int i = y; i < 32; i += 8) t[i][x] = w[(size_t)(r0 + i) * C + c0 + x];
    __syncthreads();
    for (int i = y; i < 32; i += 8) wt[(size_t)(c0 + i) * R + r0 + x] = f2bf(t[x][i]);
}

// Interleaved concat transpose for gate_w & inp_w:
//   B_cat row r (r in [0,2048)): source = (r&16) ? inp_w : gate_w,
//   channel ch = ((r>>5)<<4) | (r&15);  B_cat[r][k] = w[k][ch]  (bf16)
// So rows 32t..32t+15 = gate ch 16t..16t+15, rows 32t+16..32t+31 = inp, same ch.
__global__ __launch_bounds__(256) void k_transpose_cat(const float* __restrict__ gw,
                                                       const float* __restrict__ iw,
                                                       u16* __restrict__ wt, int K, int C) {
    __shared__ float t[32][33];
    int c0 = blockIdx.x * 32, r0 = blockIdx.y * 32;   // c0: channel block, r0: K block
    const float* w = blockIdx.z ? iw : gw;
    int x = threadIdx.x & 31, y = threadIdx.x >> 5;
    for (int i = y; i < 32; i += 8) t[i][x] = w[(size_t)(r0 + i) * C + c0 + x];
    __syncthreads();
    for (int i = y; i < 32; i += 8) {
        int ch = c0 + i;
        int r = ((ch >> 4) << 5) | ((int)blockIdx.z << 4) | (ch & 15);
        wt[(size_t)r * K + r0 + x] = f2bf(t[x][i]);
    }
}

// ---------------- fused gate GEMM (concat-N, single accumulator) ----------------
// A: [M,K] bf16. Bcat: [2N, K] bf16 interleaved (see k_transpose_cat).
// Computes P = A @ Bcat^T  [M, 2N]; epilogue pairs frag n=2t (gate) with
// n=2t+1 (inp) -> a = sigmoid(pg+gb), b = (1-a)*(pi+ib), both written bf16 [M,N].

__global__ __launch_bounds__(256) void k_gemm_cat(
    const u16* __restrict__ A, const u16* __restrict__ Bcat,
    const float* __restrict__ gb, const float* __restrict__ ib,
    u16* __restrict__ aout, u16* __restrict__ bout, int M, int N2, int K) {
    __shared__ __align__(16) u16 sA[128 * 64];
    __shared__ __align__(16) u16 sB[128 * 64];
    const int tid = threadIdx.x, lane = tid & 63, wv = tid >> 6;
    const int wr = wv >> 1, wc = wv & 1;

    // XCD-aware swizzle (nwg = 16*128 = 2048, divisible by 8)
    const int nbx = gridDim.x;                       // 16
    int fid = (int)blockIdx.y * nbx + (int)blockIdx.x;
    int nwg = nbx * (int)gridDim.y;
    int cpx = nwg >> 3;
    int swz = (fid & 7) * cpx + (fid >> 3);
    const long bm = swz / nbx, bn = swz % nbx;

    const u16* Ab = A + bm * 128 * (long)K;
    const u16* Bb = Bcat + bn * 128 * (long)K;

    f32x4 acc[4][4] = {};

    for (int kt = 0; kt < K; kt += 64) {
#pragma unroll
        for (int p = 0; p < 4; ++p) {
            int chunk = p * 256 + tid;            // 16B chunk id
            int row = chunk >> 3, kc = (chunk & 7) << 3;
            int lbase = (p * 256 + (wv << 6)) << 3;  // wave-uniform LDS base (u16 units)
            long goff = (long)row * K + kt + kc;
            gload16(Ab + goff, sA + lbase);
            gload16(Bb + goff, sB + lbase);
        }
        __syncthreads();
#pragma unroll
        for (int kk = 0; kk < 2; ++kk) {
            const int ko = kk * 32 + ((lane >> 4) << 3);
            const int r = lane & 15;
            bf16x8 af[4], bf[4];
#pragma unroll
            for (int m = 0; m < 4; ++m)
                af[m] = *(const bf16x8*)&sA[((wr * 64 + m * 16 + r) << 6) + ko];
#pragma unroll
            for (int n = 0; n < 4; ++n)
                bf[n] = *(const bf16x8*)&sB[((wc * 64 + n * 16 + r) << 6) + ko];
#pragma unroll
            for (int m = 0; m < 4; ++m)
#pragma unroll
                for (int n = 0; n < 4; ++n)
                    acc[m][n] = __builtin_amdgcn_mfma_f32_16x16x32_bf16(af[m], bf[n], acc[m][n], 0, 0, 0);
        }
        __syncthreads();
    }

    // epilogue: frag n=2t -> gate, n=2t+1 -> inp, same channels same lanes
    const int N = N2 >> 1;                                  // 1024
    const long mbase = bm * 128 + wr * 64;
    const int nbase = (int)bn * 128 + wc * 64;              // concat-col base
#pragma unroll
    for (int t = 0; t < 2; ++t) {
        int ch = (nbase >> 1) + 16 * t + (lane & 15);
        float g0 = gb[ch], i0 = ib[ch];
#pragma unroll
        for (int m = 0; m < 4; ++m) {
            long row = mbase + m * 16 + ((lane >> 4) << 2);
#pragma unroll
            for (int i = 0; i < 4; ++i) {
                float pg = acc[m][2 * t][i] + g0;
                float pi = acc[m][2 * t + 1][i] + i0;
                float aa = 1.0f / (1.0f + __expf(-pg));
                float bb = (1.0f - aa) * pi;
                long o = (row + i) * (long)N + ch;
                aout[o] = f2bf(aa);
                bout[o] = f2bf(bb);
            }
        }
    }
}

// ---------------- final GEMM: out = h @ out_w + x + out_b ----------------

__global__ __launch_bounds__(256) void k_gemm_out(
    const u16* __restrict__ A, const u16* __restrict__ Bt,
    const float* __restrict__ xres, const float* __restrict__ ob,
    float* __restrict__ out, int M, int N, int K) {
    __shared__ __align__(16) u16 sA[128 * 64];
    __shared__ __align__(16) u16 sB[128 * 64];
    const int tid = threadIdx.x, lane = tid & 63, wv = tid >> 6;
    const int wr = wv >> 1, wc = wv & 1;

    const int nbx = gridDim.x;                       // 8
    int fid = (int)blockIdx.y * nbx + (int)blockIdx.x;
    int nwg = nbx * (int)gridDim.y;
    int cpx = nwg >> 3;
    int swz = (fid & 7) * cpx + (fid >> 3);
    const long bm = swz / nbx, bn = swz % nbx;

    const u16* Ab = A + bm * 128 * (long)K;
    const u16* Bb = Bt + bn * 128 * (long)K;

    f32x4 acc[4][4] = {};

    for (int kt = 0; kt < K; kt += 64) {
#pragma unroll
        for (int p = 0; p < 4; ++p) {
            int chunk = p * 256 + tid;
            int row = chunk >> 3, kc = (chunk & 7) << 3;
            int lbase = (p * 256 + (wv << 6)) << 3;
            long goff = (long)row * K + kt + kc;
            gload16(Ab + goff, sA + lbase);
            gload16(Bb + goff, sB + lbase);
        }
        __syncthreads();
#pragma unroll
        for (int kk = 0; kk < 2; ++kk) {
            const int ko = kk * 32 + ((lane >> 4) << 3);
            const int r = lane & 15;
            bf16x8 af[4], bf[4];
#pragma unroll
            for (int m = 0; m < 4; ++m)
                af[m] = *(const bf16x8*)&sA[((wr * 64 + m * 16 + r) << 6) + ko];
#pragma unroll
            for (int n = 0; n < 4; ++n)
                bf[n] = *(const bf16x8*)&sB[((wc * 64 + n * 16 + r) << 6) + ko];
#pragma unroll
            for (int m = 0; m < 4; ++m)
#pragma unroll
                for (int n = 0; n < 4; ++n)
                    acc[m][n] = __builtin_amdgcn_mfma_f32_16x16x32_bf16(af[m], bf[n], acc[m][n], 0, 0, 0);
        }
        __syncthreads();
    }

    const long mbase = bm * 128 + wr * 64;
    const int nbase = (int)bn * 128 + wc * 64;
#pragma unroll
    for (int n = 0; n < 4; ++n) {
        int col = nbase + n * 16 + (lane & 15);
        float o0 = ob[col];
#pragma unroll
        for (int m = 0; m < 4; ++m) {
            long row = mbase + m * 16 + ((lane >> 4) << 2);
#pragma unroll
            for (int i = 0; i < 4; ++i) {
                long o = (row + i) * (long)N + col;
                out[o] = acc[m][n][i] + o0 + xres[o];
            }
        }
    }
}

// ---------------- chunked affine scan ----------------
// h_t = a_t * h_{t-1} + b_t over s in [0,4096), per (batch, channel).
// 64 chunks x 64 steps. Channels processed 2-per-thread (u32 = 2 x bf16).

#define SCAN_C 64
#define SCAN_L 64

__global__ __launch_bounds__(256) void k_scan_phaseA(
    const u32* __restrict__ a, const u32* __restrict__ b,
    float2* __restrict__ cA, float2* __restrict__ cB) {
    int e2 = blockIdx.x * 256 + threadIdx.x;  // 0..511  (channel pair)
    int c = blockIdx.y, bt = blockIdx.z;
    long base = ((long)bt * 4096 + (long)c * SCAN_L) * 512 + e2;
    float A0 = 1.f, A1 = 1.f, H0 = 0.f, H1 = 0.f;
#pragma unroll 4
    for (int i = 0; i < SCAN_L; ++i) {
        u32 av = a[base + (long)i * 512];
        u32 bv = b[base + (long)i * 512];
        float a0 = bf2f((u16)av), a1 = bf2f((u16)(av >> 16));
        float b0 = bf2f((u16)bv), b1 = bf2f((u16)(bv >> 16));
        H0 = a0 * H0 + b0;  H1 = a1 * H1 + b1;
        A0 *= a0;           A1 *= a1;
    }
    long sidx = ((long)bt * SCAN_C + c) * 512 + e2;
    cA[sidx] = make_float2(A0, A1);
    cB[sidx] = make_float2(H0, H1);
}

__global__ __launch_bounds__(256) void k_scan_phaseB(
    const float2* __restrict__ cA, const float2* __restrict__ cB,
    float2* __restrict__ hin) {
    int e2 = blockIdx.x * 256 + threadIdx.x;  // 0..511
    int bt = blockIdx.y;
    float H0 = 0.f, H1 = 0.f;
    for (int c = 0; c < SCAN_C; ++c) {
        long idx = ((long)bt * SCAN_C + c) * 512 + e2;
        hin[idx] = make_float2(H0, H1);
        float2 Av = cA[idx], Bv = cB[idx];
        H0 = Av.x * H0 + Bv.x;
        H1 = Av.y * H1 + Bv.y;
    }
}

__global__ __launch_bounds__(256) void k_scan_phaseC(
    const u32* __restrict__ a, const u32* __restrict__ b,
    const float2* __restrict__ hin, u32* __restrict__ hout) {
    int e2 = blockIdx.x * 256 + threadIdx.x;
    int c = blockIdx.y, bt = blockIdx.z;
    long base = ((long)bt * 4096 + (long)c * SCAN_L) * 512 + e2;
    long sidx = ((long)bt * SCAN_C + c) * 512 + e2;
    float2 H = hin[sidx];
    float H0 = H.x, H1 = H.y;
#pragma unroll 4
    for (int i = 0; i < SCAN_L; ++i) {
        u32 av = a[base + (long)i * 512];
        u32 bv = b[base + (long)i * 512];
        float a0 = bf2f((u16)av), a1 = bf2f((u16)(av >> 16));
        float b0 = bf2f((u16)bv), b1 = bf2f((u16)(bv >> 16));
        H0 = a0 * H0 + b0;  H1 = a1 * H1 + b1;
        hout[base + (long)i * 512] = (u32)f2bf(H0) | ((u32)f2bf(H1) << 16);
    }
}

// ---------------- launch ----------------

extern "C" void kernel_launch(void* const* d_in, const int* in_sizes, int n_in,
                              void* d_out, int out_size, void* d_ws, size_t ws_size,
                              hipStream_t stream) {
    const float* x      = (const float*)d_in[0];
    const float* gate_w = (const float*)d_in[1];
    const float* gate_b = (const float*)d_in[2];
    const float* inp_w  = (const float*)d_in[3];
    const float* inp_b  = (const float*)d_in[4];
    const float* out_w  = (const float*)d_in[5];
    const float* out_b  = (const float*)d_in[6];
    float* out = (float*)d_out;

    const int Bsz = 4, S = 4096, Din = 1024, Dst = 1024;
    const int M = Bsz * S;                 // 16384
    const long nx = (long)M * Din;         // 16777216

    // workspace layout (bytes)
    char* w = (char*)d_ws;
    u16* xb     = (u16*)(w);                  // 33,554,432  x bf16
    u16* catW   = (u16*)(w + 33554432);       //  4,194,304  interleaved [gate;inp]^T bf16
    u16* owT    = (u16*)(w + 37748736);       //  2,097,152  out_w^T  bf16
    u16* hbf    = (u16*)(w + 39845888);       // 33,554,432  scan_out bf16
    float2* cA  = (float2*)(w + 73400320);    //  1,048,576  chunk A-products
    float2* cB  = (float2*)(w + 74448896);    //  1,048,576  chunk B-offsets
    float2* hin = (float2*)(w + 75497472);    //  1,048,576  chunk incoming states
    // total 76,546,048 B

    // a, b (bf16) live in d_out (exactly 67,108,864 B); overwritten by final GEMM.
    u16* abf = (u16*)d_out;
    u16* bbf = abf + nx;

    // 1. conversions
    k_cvt_x<<<(int)(nx / 4 / 256), 256, 0, stream>>>((const float4*)x, (uint2*)xb, (int)(nx / 4));
    k_transpose_cat<<<dim3(Dst / 32, Din / 32, 2), 256, 0, stream>>>(gate_w, inp_w, catW, Din, Dst);
    k_transpose_bf<<<dim3(Din / 32, Dst / 32), 256, 0, stream>>>(out_w, owT, Dst, Din);

    // 2. fused concat GEMM -> a, b
    k_gemm_cat<<<dim3(2 * Dst / 128, M / 128), 256, 0, stream>>>(
        xb, catW, gate_b, inp_b, abf, bbf, M, 2 * Dst, Din);

    // 3. chunked scan -> h (bf16)
    k_scan_phaseA<<<dim3(2, SCAN_C, Bsz), 256, 0, stream>>>((const u32*)abf, (const u32*)bbf, cA, cB);
    k_scan_phaseB<<<dim3(2, Bsz), 256, 0, stream>>>(cA, cB, hin);
    k_scan_phaseC<<<dim3(2, SCAN_C, Bsz), 256, 0, stream>>>((const u32*)abf, (const u32*)bbf, hin, (u32*)hbf);

    // 4. final GEMM: out = h @ out_w + x + out_b
    k_gemm_out<<<dim3(Din / 128, M / 128), 256, 0, stream>>>(
        hbf, owT, x, out_b, out, M, Din, Dst);
}

// Round 4
// 192.499 us; speedup vs baseline: 1.4529x; 1.2139x over previous
//
#include <hip/hip_runtime.h>

typedef unsigned short u16;
typedef unsigned int   u32;
typedef __bf16 bf16x8 __attribute__((ext_vector_type(8)));
typedef float  f32x4  __attribute__((ext_vector_type(4)));

#define DEVI __device__ __forceinline__

DEVI u16 f2bf(float f) {
    union { float f; u32 u; } c; c.f = f;
    u32 u = c.u;
    u32 r = (u + 0x7fffu + ((u >> 16) & 1u)) >> 16;
    return (u16)r;
}
DEVI float bf2f(u16 v) {
    union { u32 u; float f; } c; c.u = ((u32)v) << 16;
    return c.f;
}

DEVI void gload16(const void* g, void* l) {
    __builtin_amdgcn_global_load_lds(
        (const __attribute__((address_space(1))) void*)g,
        (__attribute__((address_space(3))) void*)l, 16, 0, 0);
}

// ---------------- 256x256 8-phase GEMM machinery ----------------
// LDS (u16 units): buffer b at b*32768; within buffer:
//   A kh0 @0, A kh1 @8192, B kh0 @16384, B kh1 @24576
// Each kh-slot: [256 rows][32 cols] bf16, 64B row stride -> ds_read_b128
// fragments are bank-conflict-free by construction.
//
// Sync rule (the round-3 race fix): vmcnt is PER-WAVE, but each slot is
// staged by all 8 waves. So every counted VMW sits BEFORE a closing
// s_barrier; the barrier globalizes per-wave load completion. Phases whose
// successor reads freshly-staged slots end with MMEV(N); others with MME.

#define VMW(N)  asm volatile("s_waitcnt vmcnt(" #N ")" ::: "memory")
#define BAR     __builtin_amdgcn_s_barrier()
#define MMP     BAR; asm volatile("s_waitcnt lgkmcnt(0)" ::: "memory"); \
                __builtin_amdgcn_sched_barrier(0); __builtin_amdgcn_s_setprio(1)
#define MME     __builtin_amdgcn_s_setprio(0); BAR
#define MMEV(N) __builtin_amdgcn_s_setprio(0); VMW(N); BAR

// stage one kh half-tile: 256 rows x 32 cols bf16 = 16KB, 2 x 16B per thread
DEVI void stage_kh(const u16* g, u16* slot, int tid) {
    const int K = 1024;
    const int wvb = (tid >> 6) << 9;             // wave base (u16)
    const int r = tid >> 2, c = (tid & 3) << 3;  // row 0..127, col chunk
    const long off = (long)r * K + c;
    gload16(g + off, slot + wvb);
    gload16(g + off + (long)128 * K, slot + 4096 + wvb);
}

DEVI void lda4(bf16x8 a[4], const u16* base, int mh) {
#pragma unroll
    for (int q = 0; q < 4; ++q)
        a[q] = *(const bf16x8*)(base + mh * 2048 + q * 512);
}
DEVI void ldb4(bf16x8 b[4], const u16* base) {
#pragma unroll
    for (int n = 0; n < 4; ++n)
        b[n] = *(const bf16x8*)(base + n * 512);
}
DEVI void mm16(f32x4 (&acc)[8][4], const bf16x8 a[4], const bf16x8 b[4], int mh) {
#pragma unroll
    for (int q = 0; q < 4; ++q)
#pragma unroll
        for (int n = 0; n < 4; ++n)
            acc[mh * 4 + q][n] =
                __builtin_amdgcn_mfma_f32_16x16x32_bf16(a[q], b[n], acc[mh * 4 + q][n], 0, 0, 0);
}

// Full K=1024 pipeline: 16 K-tiles, 7 iterations x 8 phases + peeled tail.
DEVI void pipeline(const u16* Ablk, const u16* Bblk, u16* lds,
                   f32x4 (&acc)[8][4], int tid) {
    const int lane = tid & 63;
    const int wm = (tid >> 6) >> 2, wn = (tid >> 6) & 3;
    const int aoff = wm * 4096 + (lane & 15) * 32 + ((lane >> 4) << 3);
    const int boff = 16384 + wn * 2048 + (lane & 15) * 32 + ((lane >> 4) << 3);
    u16* b0 = lds;
    u16* b1 = lds + 32768;

    // prologue: s1..s7 (t1.Akh1 is staged at iter0.ph0)
    stage_kh(Bblk,      b0 + 16384, tid);   // s1 t0.B0
    stage_kh(Ablk,      b0,         tid);   // s2 t0.A0
    stage_kh(Bblk + 32, b0 + 24576, tid);   // s3 t0.B1
    stage_kh(Ablk + 32, b0 + 8192,  tid);   // s4 t0.A1
    stage_kh(Bblk + 64, b1 + 16384, tid);   // s5 t1.B0
    stage_kh(Ablk + 64, b1,         tid);   // s6 t1.A0
    stage_kh(Bblk + 96, b1 + 24576, tid);   // s7 t1.B1
    VMW(10); BAR;                           // gate ph0 reads (s1,s2) globally

    bf16x8 af[4], bfr[4];

#pragma unroll 1
    for (int j = 0; j < 7; ++j) {
        const u16* Aod = Ablk + (2 * j + 1) * 64;
        const u16* At2 = Ablk + (2 * j + 2) * 64;
        const u16* Bt2 = Bblk + (2 * j + 2) * 64;
        // ph0: buf0 kh0 mh0 (+B)   stage t(2j+1).Akh1 -> b1.A1
        lda4(af, b0 + aoff, 0); ldb4(bfr, b0 + boff);
        stage_kh(Aod + 32, b1 + 8192, tid);
        MMP; mm16(acc, af, bfr, 0); MME;
        // ph1: buf0 kh0 mh1        stage t+2.Bkh0 -> b0.B0   [gate ph2]
        lda4(af, b0 + aoff, 1);
        stage_kh(Bt2, b0 + 16384, tid);
        MMP; mm16(acc, af, bfr, 1); MMEV(10);
        // ph2: buf0 kh1 mh0 (+B)   stage t+2.Akh0 -> b0.A0
        lda4(af, b0 + 8192 + aoff, 0); ldb4(bfr, b0 + 8192 + boff);
        stage_kh(At2, b0, tid);
        MMP; mm16(acc, af, bfr, 0); MME;
        // ph3: buf0 kh1 mh1        stage t+2.Bkh1 -> b0.B1   [gate ph4]
        lda4(af, b0 + 8192 + aoff, 1);
        stage_kh(Bt2 + 32, b0 + 24576, tid);
        MMP; mm16(acc, af, bfr, 1); MMEV(10);
        // ph4: buf1 kh0 mh0 (+B)   stage t+2.Akh1 -> b0.A1
        lda4(af, b1 + aoff, 0); ldb4(bfr, b1 + boff);
        stage_kh(At2 + 32, b0 + 8192, tid);
        MMP; mm16(acc, af, bfr, 0); MME;
        // ph5: buf1 kh0 mh1        stage t+3.Bkh0 -> b1.B0   [gate ph6]
        lda4(af, b1 + aoff, 1);
        stage_kh(Bt2 + 64, b1 + 16384, tid);
        MMP; mm16(acc, af, bfr, 1); MMEV(10);
        // ph6: buf1 kh1 mh0 (+B)   stage t+3.Akh0 -> b1.A0
        lda4(af, b1 + 8192 + aoff, 0); ldb4(bfr, b1 + 8192 + boff);
        stage_kh(At2 + 64, b1, tid);
        MMP; mm16(acc, af, bfr, 0); MME;
        // ph7: buf1 kh1 mh1        stage t+3.Bkh1 -> b1.B1   [gate next ph0]
        lda4(af, b1 + 8192 + aoff, 1);
        stage_kh(Bt2 + 96, b1 + 24576, tid);
        MMP; mm16(acc, af, bfr, 1); MMEV(10);
    }
    // peeled tail: tiles 14 (b0), 15 (b1); drain 8 -> 4 -> 0
    {
        const u16* Aod = Ablk + 15 * 64;
        lda4(af, b0 + aoff, 0); ldb4(bfr, b0 + boff);
        stage_kh(Aod + 32, b1 + 8192, tid);           // s64 t15.A1
        MMP; mm16(acc, af, bfr, 0); MME;
        lda4(af, b0 + aoff, 1);
        MMP; mm16(acc, af, bfr, 1); MMEV(8);
        lda4(af, b0 + 8192 + aoff, 0); ldb4(bfr, b0 + 8192 + boff);
        MMP; mm16(acc, af, bfr, 0); MME;
        lda4(af, b0 + 8192 + aoff, 1);
        MMP; mm16(acc, af, bfr, 1); MMEV(4);
        lda4(af, b1 + aoff, 0); ldb4(bfr, b1 + boff);
        MMP; mm16(acc, af, bfr, 0); MME;
        lda4(af, b1 + aoff, 1);
        MMP; mm16(acc, af, bfr, 1); MMEV(0);
        lda4(af, b1 + 8192 + aoff, 0); ldb4(bfr, b1 + 8192 + boff);
        MMP; mm16(acc, af, bfr, 0); MME;
        lda4(af, b1 + 8192 + aoff, 1);
        MMP; mm16(acc, af, bfr, 1); MME;
    }
}

// ---------------- gate GEMM: P = A @ Bcat^T, fused sigmoid-gate epilogue ----
// writes packed ab[row*1024 + ch] = bf16(a) | bf16(b)<<16

__global__ __launch_bounds__(512, 2) void k_gemm_cat8(
    const u16* __restrict__ A, const u16* __restrict__ Bcat,
    const float* __restrict__ gb, const float* __restrict__ ib,
    u32* __restrict__ ab) {
    __shared__ __align__(16) u16 lds[65536];
    const int tid = threadIdx.x, lane = tid & 63;
    const int wm = (tid >> 6) >> 2, wn = (tid >> 6) & 3;

    // bijective XCD swizzle, grid (8, 64) = 512 wg
    int fid = (int)blockIdx.y * 8 + (int)blockIdx.x;
    int swz = (fid & 7) * 64 + (fid >> 3);
    const long bn = swz & 7, bm = swz >> 3;

    f32x4 acc[8][4] = {};
    pipeline(A + bm * 256 * 1024, Bcat + bn * 256 * 1024, lds, acc, tid);

    const long rbase = bm * 256 + wm * 128;
    const int chbase = (int)bn * 128 + wn * 32;
#pragma unroll
    for (int t = 0; t < 2; ++t) {
        int ch = chbase + t * 16 + (lane & 15);
        float g0 = gb[ch], i0 = ib[ch];
#pragma unroll
        for (int m = 0; m < 8; ++m) {
            long row = rbase + m * 16 + ((lane >> 4) << 2);
#pragma unroll
            for (int i = 0; i < 4; ++i) {
                float pg = acc[m][2 * t][i] + g0;
                float pi = acc[m][2 * t + 1][i] + i0;
                float aa = 1.0f / (1.0f + __expf(-pg));
                float bb = (1.0f - aa) * pi;
                ab[(row + i) * 1024 + ch] = (u32)f2bf(aa) | ((u32)f2bf(bb) << 16);
            }
        }
    }
}

// ---------------- final GEMM: out = h @ out_w + x + out_b ----------------

__global__ __launch_bounds__(512, 2) void k_gemm_out8(
    const u16* __restrict__ A, const u16* __restrict__ Bt,
    const float* __restrict__ xres, const float* __restrict__ ob,
    float* __restrict__ out) {
    __shared__ __align__(16) u16 lds[65536];
    const int tid = threadIdx.x, lane = tid & 63;
    const int wm = (tid >> 6) >> 2, wn = (tid >> 6) & 3;

    // bijective XCD swizzle, grid (4, 64) = 256 wg
    int fid = (int)blockIdx.y * 4 + (int)blockIdx.x;
    int swz = (fid & 7) * 32 + (fid >> 3);
    const long bn = swz & 3, bm = swz >> 2;

    f32x4 acc[8][4] = {};
    pipeline(A + bm * 256 * 1024, Bt + bn * 256 * 1024, lds, acc, tid);

    const long rbase = bm * 256 + wm * 128;
    const int cbase = (int)bn * 256 + wn * 64;
#pragma unroll
    for (int n = 0; n < 4; ++n) {
        int col = cbase + n * 16 + (lane & 15);
        float o0 = ob[col];
#pragma unroll
        for (int m = 0; m < 8; ++m) {
            long row = rbase + m * 16 + ((lane >> 4) << 2);
#pragma unroll
            for (int i = 0; i < 4; ++i) {
                long o = (row + i) * 1024 + col;
                out[o] = acc[m][n][i] + o0 + xres[o];
            }
        }
    }
}

// ---------------- conversions ----------------

__global__ __launch_bounds__(256) void k_cvt_x(const float4* __restrict__ x,
                                               uint2* __restrict__ o, int n4) {
    int i = blockIdx.x * 256 + threadIdx.x;
    if (i < n4) {
        float4 v = x[i];
        uint2 r;
        r.x = (u32)f2bf(v.x) | ((u32)f2bf(v.y) << 16);
        r.y = (u32)f2bf(v.z) | ((u32)f2bf(v.w) << 16);
        o[i] = r;
    }
}

__global__ __launch_bounds__(256) void k_transpose_bf(const float* __restrict__ w,
                                                      u16* __restrict__ wt, int R, int C) {
    __shared__ float t[32][33];
    int c0 = blockIdx.x * 32, r0 = blockIdx.y * 32;
    int x = threadIdx.x & 31, y = threadIdx.x >> 5;
    for (int i = y; i < 32; i += 8) t[i][x] = w[(size_t)(r0 + i) * C + c0 + x];
    __syncthreads();
    for (int i = y; i < 32; i += 8) wt[(size_t)(c0 + i) * R + r0 + x] = f2bf(t[x][i]);
}

// Interleaved concat transpose: rows 32t..32t+15 = gate ch 16t..16t+15,
// rows 32t+16..32t+31 = inp, same channels.
__global__ __launch_bounds__(256) void k_transpose_cat(const float* __restrict__ gw,
                                                       const float* __restrict__ iw,
                                                       u16* __restrict__ wt, int K, int C) {
    __shared__ float t[32][33];
    int c0 = blockIdx.x * 32, r0 = blockIdx.y * 32;
    const float* w = blockIdx.z ? iw : gw;
    int x = threadIdx.x & 31, y = threadIdx.x >> 5;
    for (int i = y; i < 32; i += 8) t[i][x] = w[(size_t)(r0 + i) * C + c0 + x];
    __syncthreads();
    for (int i = y; i < 32; i += 8) {
        int ch = c0 + i;
        int r = ((ch >> 4) << 5) | ((int)blockIdx.z << 4) | (ch & 15);
        wt[(size_t)r * K + r0 + x] = f2bf(t[x][i]);
    }
}

// ---------------- chunked affine scan (packed ab stream) ----------------
// ab[row*1024 + ch]: lo = a (bf16), hi = b (bf16). h_t = a*h + b over s.

__global__ __launch_bounds__(256) void k_scanA(const u32* __restrict__ ab,
                                               float* __restrict__ cA,
                                               float* __restrict__ cB) {
    int e = blockIdx.x * 256 + threadIdx.x;  // 0..1023
    int c = blockIdx.y, bt = blockIdx.z;
    long base = ((long)bt * 4096 + c * 64) * 1024 + e;
    float Aa = 1.f, H = 0.f;
#pragma unroll 4
    for (int i = 0; i < 64; ++i) {
        u32 v = ab[base + (long)i * 1024];
        float a = bf2f((u16)v), b = bf2f((u16)(v >> 16));
        H = a * H + b;
        Aa *= a;
    }
    long s = ((long)bt * 64 + c) * 1024 + e;
    cA[s] = Aa; cB[s] = H;
}

__global__ __launch_bounds__(256) void k_scanB(const float* __restrict__ cA,
                                               const float* __restrict__ cB,
                                               float* __restrict__ hin) {
    int e = blockIdx.x * 256 + threadIdx.x;
    int bt = blockIdx.y;
    float H = 0.f;
    for (int c = 0; c < 64; ++c) {
        long s = ((long)bt * 64 + c) * 1024 + e;
        hin[s] = H;
        H = cA[s] * H + cB[s];
    }
}

__global__ __launch_bounds__(256) void k_scanC(const u32* __restrict__ ab,
                                               const float* __restrict__ hin,
                                               u16* __restrict__ hout) {
    int e = blockIdx.x * 256 + threadIdx.x;
    int c = blockIdx.y, bt = blockIdx.z;
    long base = ((long)bt * 4096 + c * 64) * 1024 + e;
    float H = hin[((long)bt * 64 + c) * 1024 + e];
#pragma unroll 4
    for (int i = 0; i < 64; ++i) {
        u32 v = ab[base + (long)i * 1024];
        H = bf2f((u16)v) * H + bf2f((u16)(v >> 16));
        hout[base + (long)i * 1024] = f2bf(H);
    }
}

// ---------------- launch ----------------

extern "C" void kernel_launch(void* const* d_in, const int* in_sizes, int n_in,
                              void* d_out, int out_size, void* d_ws, size_t ws_size,
                              hipStream_t stream) {
    const float* x      = (const float*)d_in[0];
    const float* gate_w = (const float*)d_in[1];
    const float* gate_b = (const float*)d_in[2];
    const float* inp_w  = (const float*)d_in[3];
    const float* inp_b  = (const float*)d_in[4];
    const float* out_w  = (const float*)d_in[5];
    const float* out_b  = (const float*)d_in[6];
    float* out = (float*)d_out;

    const int Bsz = 4, S = 4096, Din = 1024, Dst = 1024;
    const int M = Bsz * S;                 // 16384
    const long nx = (long)M * Din;         // 16777216

    // workspace layout (bytes)
    char* w = (char*)d_ws;
    u16* xb    = (u16*)(w);                  // 33,554,432  x bf16
    u16* catW  = (u16*)(w + 33554432);       //  4,194,304  [gate;inp] interleaved ^T
    u16* owT   = (u16*)(w + 37748736);       //  2,097,152  out_w^T bf16
    u16* hbf   = (u16*)(w + 39845888);       // 33,554,432  scan_out bf16
    float* cA  = (float*)(w + 73400320);     //  1,048,576
    float* cB  = (float*)(w + 74448896);     //  1,048,576
    float* hin = (float*)(w + 75497472);     //  1,048,576
    // total 76,546,048 B

    // packed ab lives in d_out (67,108,864 B); overwritten by final GEMM.
    u32* ab = (u32*)d_out;

    // 1. conversions
    k_cvt_x<<<(int)(nx / 4 / 256), 256, 0, stream>>>((const float4*)x, (uint2*)xb, (int)(nx / 4));
    k_transpose_cat<<<dim3(Dst / 32, Din / 32, 2), 256, 0, stream>>>(gate_w, inp_w, catW, Din, Dst);
    k_transpose_bf<<<dim3(Din / 32, Dst / 32), 256, 0, stream>>>(out_w, owT, Dst, Din);

    // 2. fused concat GEMM -> packed ab
    k_gemm_cat8<<<dim3(8, M / 256), 512, 0, stream>>>(xb, catW, gate_b, inp_b, ab);

    // 3. chunked scan -> h (bf16)
    k_scanA<<<dim3(4, 64, Bsz), 256, 0, stream>>>(ab, cA, cB);
    k_scanB<<<dim3(4, Bsz), 256, 0, stream>>>(cA, cB, hin);
    k_scanC<<<dim3(4, 64, Bsz), 256, 0, stream>>>(ab, hin, hbf);

    // 4. final GEMM: out = h @ out_w + x + out_b
    k_gemm_out8<<<dim3(4, M / 256), 512, 0, stream>>>(hbf, owT, x, out_b, out);
}